// Round 10
// baseline (185.996 us; speedup 1.0000x reference)
//
#include <hip/hip_runtime.h>
#include <hip/hip_cooperative_groups.h>

namespace cg = cooperative_groups;

#define G 64
#define C 32
#define D 18432
#define QCOLS 4608            // cols per block (group-quarter)
#define NSTEP (QCOLS / 256)   // 18 k-steps (8 waves x 32 cols)
#define EPS 1e-5f
#define NS_ITERS 5
// fallback (R9) geometry
#define NCH 16
#define TD (D / NCH)
#define NST (TD / 128)

typedef __attribute__((ext_vector_type(8))) short short8v;
typedef __attribute__((ext_vector_type(4))) float float4v;

__device__ __forceinline__ void split3(float x, unsigned short& h1,
                                       unsigned short& h2, unsigned short& h3) {
    unsigned int u = __float_as_uint(x);
    unsigned int m1 = u & 0xffff0000u;
    float r1 = x - __uint_as_float(m1);
    unsigned int u2 = __float_as_uint(r1);
    unsigned int m2 = u2 & 0xffff0000u;
    float r2 = r1 - __uint_as_float(m2);
    h1 = (unsigned short)(m1 >> 16);
    h2 = (unsigned short)(m2 >> 16);
    h3 = (unsigned short)(__float_as_uint(r2) >> 16);
}

__device__ __forceinline__ void split8(const float4& v0, const float4& v1,
                                       short8v& p1, short8v& p2, short8v& p3,
                                       float& rs) {
    float x[8] = {v0.x, v0.y, v0.z, v0.w, v1.x, v1.y, v1.z, v1.w};
#pragma unroll
    for (int j = 0; j < 8; ++j) {
        unsigned short h1, h2, h3;
        rs += x[j];
        split3(x[j], h1, h2, h3);
        p1[j] = (short)h1; p2[j] = (short)h2; p3[j] = (short)h3;
    }
}

// 6 MFMAs: 3-term split product (terms >= 2^-18 kept -> fp32-grade Gram)
#define MM6(T, A0, A1, A2, B0, B1, B2)                                        \
    T = __builtin_amdgcn_mfma_f32_16x16x32_bf16(A0, B0, T, 0, 0, 0);          \
    T = __builtin_amdgcn_mfma_f32_16x16x32_bf16(A0, B1, T, 0, 0, 0);          \
    T = __builtin_amdgcn_mfma_f32_16x16x32_bf16(A1, B0, T, 0, 0, 0);          \
    T = __builtin_amdgcn_mfma_f32_16x16x32_bf16(A1, B1, T, 0, 0, 0);          \
    T = __builtin_amdgcn_mfma_f32_16x16x32_bf16(A0, B2, T, 0, 0, 0);          \
    T = __builtin_amdgcn_mfma_f32_16x16x32_bf16(A2, B0, T, 0, 0, 0);

// ===========================================================================
// FUSED cooperative kernel: phase1 Gram -> grid.sync -> phase2 NS (redundant
// per block, removes 64-block tail + 2nd sync) -> phase3 apply (L3-warm W).
// grid = 256 blocks (1/CU), block = 512 (8 waves).
// ===========================================================================
__global__ __launch_bounds__(512, 2) void fused_all(const float* __restrict__ W,
                                                    float* __restrict__ psum,
                                                    float* __restrict__ prow,
                                                    float* __restrict__ mtb,
                                                    float* __restrict__ vvb,
                                                    float* __restrict__ out) {
    __shared__ __align__(16) float red[8704];   // 8 gram planes + 8x32 rowsums
    __shared__ float mean[C];
    __shared__ float redw[8];
    __shared__ float normsh;

    const int b    = blockIdx.x;
    const int g    = b >> 2;
    const int q    = b & 3;
    const int tid  = threadIdx.x;
    const int lane = tid & 63;
    const int wave = tid >> 6;

    // ---------------- phase 1: Gram partial over cols [q*4608, +4608) ------
    {
        const int rbase = lane & 15;
        const int koff  = (lane >> 4) * 8;
        const float* Zg = W + (size_t)g * C * D + (size_t)q * QCOLS;
        const float* p0 = Zg + (size_t)rbase * D + wave * 32 + koff;
        const float* p1 = p0 + (size_t)16 * D;

        float4v acc00 = (float4v)0.f, acc01 = (float4v)0.f;
        float4v acc10 = (float4v)0.f, acc11 = (float4v)0.f;
        float rs0 = 0.f, rs1 = 0.f;

        float4 c00 = *(const float4*)(p0);
        float4 c01 = *(const float4*)(p0 + 4);
        float4 c10 = *(const float4*)(p1);
        float4 c11 = *(const float4*)(p1 + 4);

#pragma unroll 1
        for (int st = 0; st < NSTEP; ++st) {
            float4 n00, n01, n10, n11;
            if (st + 1 < NSTEP) {
                const float* q0 = p0 + (st + 1) * 256;
                const float* q1 = p1 + (st + 1) * 256;
                n00 = *(const float4*)(q0);
                n01 = *(const float4*)(q0 + 4);
                n10 = *(const float4*)(q1);
                n11 = *(const float4*)(q1 + 4);
            }
            short8v fa0, fa1, fa2, fb0, fb1, fb2;
            split8(c00, c01, fa0, fa1, fa2, rs0);
            split8(c10, c11, fb0, fb1, fb2, rs1);

            MM6(acc00, fa0, fa1, fa2, fa0, fa1, fa2)
            MM6(acc01, fa0, fa1, fa2, fb0, fb1, fb2)
            MM6(acc10, fb0, fb1, fb2, fa0, fa1, fa2)
            MM6(acc11, fb0, fb1, fb2, fb0, fb1, fb2)

            c00 = n00; c01 = n01; c10 = n10; c11 = n11;
        }

        rs0 += __shfl_xor(rs0, 16, 64); rs0 += __shfl_xor(rs0, 32, 64);
        rs1 += __shfl_xor(rs1, 16, 64); rs1 += __shfl_xor(rs1, 32, 64);
        if (lane < 16) {
            red[8448 + wave * 32 + lane]      = rs0;
            red[8448 + wave * 32 + 16 + lane] = rs1;
        }
        {
            const int rq = (lane >> 4) << 2;   // m89-verified C/D map
            const int cl = lane & 15;
            float* base = red + wave * 1056;
#pragma unroll
            for (int j = 0; j < 4; ++j) {
                base[(rq + j) * 33 + cl]           = acc00[j];
                base[(rq + j) * 33 + 16 + cl]      = acc01[j];
                base[(16 + rq + j) * 33 + cl]      = acc10[j];
                base[(16 + rq + j) * 33 + 16 + cl] = acc11[j];
            }
        }
        __syncthreads();
#pragma unroll
        for (int k = 0; k < 2; ++k) {
            int el  = tid + 512 * k;
            int row = el >> 5, col = el & 31;
            int o   = row * 33 + col;
            float sv = 0.f;
#pragma unroll
            for (int wv = 0; wv < 8; ++wv) sv += red[wv * 1056 + o];
            psum[(size_t)b * 1024 + el] = sv;
        }
        if (tid < C) {
            float s = 0.f;
#pragma unroll
            for (int wv = 0; wv < 8; ++wv) s += red[8448 + wv * 32 + tid];
            prow[(size_t)b * 32 + tid] = s;
        }
    }

    __threadfence();
    cg::this_grid().sync();

    // ---------------- phase 2: NS per block (redundant x4 per group) -------
    {
        const int e  = tid & 31;
        const int cb = tid >> 5;      // 0..15; thread owns rows cb, cb+16
        float* Sm  = red;
        float* Bm  = red + 1056;
        float* T1m = red + 2112;
        float* T2m = red + 3168;

        float selt0 = 0.f, selt1 = 0.f;
#pragma unroll
        for (int q2 = 0; q2 < 4; ++q2) {
            const float* ps = psum + (size_t)(g * 4 + q2) * 1024;
            selt0 += ps[tid];
            selt1 += ps[tid + 512];
        }
        if (tid < C) {
            float s = 0.f;
#pragma unroll
            for (int q2 = 0; q2 < 4; ++q2) s += prow[(size_t)(g * 4 + q2) * 32 + tid];
            mean[tid] = s / (float)D;
        }
        __syncthreads();

        float ss = 0.f;
        {
            int c = cb;
            float sv = selt0 - (float)D * mean[c] * mean[e];
            if (c == e) sv += EPS;
            Sm[c * 33 + e] = sv; ss = fmaf(sv, sv, ss);
            c = cb + 16;
            sv = selt1 - (float)D * mean[c] * mean[e];
            if (c == e) sv += EPS;
            Sm[c * 33 + e] = sv; ss = fmaf(sv, sv, ss);
        }
#pragma unroll
        for (int off = 32; off >= 1; off >>= 1) ss += __shfl_xor(ss, off, 64);
        if (lane == 0) redw[wave] = ss;
        __syncthreads();
        if (tid == 0) {
            float t = 0.f;
#pragma unroll
            for (int wv = 0; wv < 8; ++wv) t += redw[wv];
            normsh = sqrtf(t);
        }
        __syncthreads();
        const float inv_norm = 1.0f / normsh;
#pragma unroll
        for (int k = 0; k < 2; ++k) {
            int c = cb + 16 * k;
            Sm[c * 33 + e] *= inv_norm;
            Bm[c * 33 + e] = (c == e) ? 1.f : 0.f;
        }
        __syncthreads();

        for (int it = 0; it < NS_ITERS; ++it) {
#pragma unroll
            for (int k = 0; k < 2; ++k) {
                int c = cb + 16 * k;
                float s = 0.f;
                for (int kk = 0; kk < C; ++kk)
                    s = fmaf(Bm[c * 33 + kk], Bm[kk * 33 + e], s);
                T1m[c * 33 + e] = s;
            }
            __syncthreads();
#pragma unroll
            for (int k = 0; k < 2; ++k) {
                int c = cb + 16 * k;
                float s = 0.f;
                for (int kk = 0; kk < C; ++kk)
                    s = fmaf(T1m[c * 33 + kk], Bm[kk * 33 + e], s);
                T2m[c * 33 + e] = s;
            }
            __syncthreads();
            float pv0 = 0.f, pv1 = 0.f;
            for (int kk = 0; kk < C; ++kk)
                pv0 = fmaf(T2m[cb * 33 + kk], Sm[kk * 33 + e], pv0);
            for (int kk = 0; kk < C; ++kk)
                pv1 = fmaf(T2m[(cb + 16) * 33 + kk], Sm[kk * 33 + e], pv1);
            Bm[cb * 33 + e]        = 1.5f * Bm[cb * 33 + e] - 0.5f * pv0;
            Bm[(cb + 16) * 33 + e] = 1.5f * Bm[(cb + 16) * 33 + e] - 0.5f * pv1;
            __syncthreads();
        }

        const float invs = 1.0f / sqrtf(normsh);
#pragma unroll
        for (int k = 0; k < 2; ++k) {
            int c = cb + 16 * k;
            mtb[(size_t)b * 1024 + e * C + c] = Bm[c * 33 + e] * invs;
        }
        if (tid < C) {
            float s = 0.f;
            for (int ee = 0; ee < C; ++ee)
                s = fmaf(Bm[tid * 33 + ee] * invs, mean[ee], s);
            vvb[(size_t)b * 32 + tid] = s;
        }
    }
    __syncthreads();   // drains vmcnt -> own-block mtb/vvb stores visible

    // ---------------- phase 3: apply on this block's quarter ---------------
    {
        const float* Mg = mtb + (size_t)b * 1024;
        const float* vg = vvb + (size_t)b * 32;
        const float* Zb = W + (size_t)g * C * D;
        float*       Ob = out + (size_t)g * C * D;

#pragma unroll 1
        for (int p = 0; p < 3; ++p) {
            int u = tid + p * 512;
            if (u < 1152) {
                const int c4 = q * 1152 + u;
                const float* Zc = Zb + (size_t)c4 * 4;
                float4 acc[C];
#pragma unroll
                for (int r = 0; r < C; ++r) acc[r] = make_float4(0.f, 0.f, 0.f, 0.f);
#pragma unroll 4
                for (int e2 = 0; e2 < C; ++e2) {
                    float4 z = *(const float4*)(Zc + (size_t)e2 * D);
#pragma unroll
                    for (int r = 0; r < C; ++r) {
                        float m = Mg[e2 * C + r];   // uniform -> s_load
                        acc[r].x = fmaf(m, z.x, acc[r].x);
                        acc[r].y = fmaf(m, z.y, acc[r].y);
                        acc[r].z = fmaf(m, z.z, acc[r].z);
                        acc[r].w = fmaf(m, z.w, acc[r].w);
                    }
                }
                float* Oc = Ob + (size_t)c4 * 4;
#pragma unroll
                for (int r = 0; r < C; ++r) {
                    float vr = vg[r];
                    float4 o = make_float4(acc[r].x - vr, acc[r].y - vr,
                                           acc[r].z - vr, acc[r].w - vr);
                    *(float4*)(Oc + (size_t)r * D) = o;
                }
            }
        }
    }
}

// ===========================================================================
// Fallback path: R9's three kernels, verbatim (known-pass at 95 us)
// ===========================================================================
__global__ __launch_bounds__(256) void k1_gram(const float* __restrict__ W,
                                               float* __restrict__ psum,
                                               float* __restrict__ prow) {
    __shared__ float red[4 * 1056 + 4 * C];
    const int ch   = blockIdx.x;
    const int g    = blockIdx.y;
    const int bid  = g * NCH + ch;
    const int tid  = threadIdx.x;
    const int lane = tid & 63;
    const int wave = tid >> 6;
    const int rbase = lane & 15;
    const int koff  = (lane >> 4) * 8;
    const float* Zg = W + (size_t)g * C * D + (size_t)ch * TD;
    const float* p0 = Zg + (size_t)rbase * D + wave * 32 + koff;
    const float* p1 = p0 + (size_t)16 * D;
    float4v acc00 = (float4v)0.f, acc01 = (float4v)0.f;
    float4v acc10 = (float4v)0.f, acc11 = (float4v)0.f;
    float rs0 = 0.f, rs1 = 0.f;
    float4 c00 = *(const float4*)(p0);
    float4 c01 = *(const float4*)(p0 + 4);
    float4 c10 = *(const float4*)(p1);
    float4 c11 = *(const float4*)(p1 + 4);
#pragma unroll 1
    for (int st = 0; st < NST; ++st) {
        float4 n00, n01, n10, n11;
        if (st + 1 < NST) {
            const float* q0 = p0 + (st + 1) * 128;
            const float* q1 = p1 + (st + 1) * 128;
            n00 = *(const float4*)(q0);
            n01 = *(const float4*)(q0 + 4);
            n10 = *(const float4*)(q1);
            n11 = *(const float4*)(q1 + 4);
        }
        short8v fa0, fa1, fa2, fb0, fb1, fb2;
        split8(c00, c01, fa0, fa1, fa2, rs0);
        split8(c10, c11, fb0, fb1, fb2, rs1);
        MM6(acc00, fa0, fa1, fa2, fa0, fa1, fa2)
        MM6(acc01, fa0, fa1, fa2, fb0, fb1, fb2)
        MM6(acc10, fb0, fb1, fb2, fa0, fa1, fa2)
        MM6(acc11, fb0, fb1, fb2, fb0, fb1, fb2)
        c00 = n00; c01 = n01; c10 = n10; c11 = n11;
    }
    rs0 += __shfl_xor(rs0, 16, 64); rs0 += __shfl_xor(rs0, 32, 64);
    rs1 += __shfl_xor(rs1, 16, 64); rs1 += __shfl_xor(rs1, 32, 64);
    if (lane < 16) {
        red[4224 + wave * C + lane]      = rs0;
        red[4224 + wave * C + 16 + lane] = rs1;
    }
    {
        const int rq = (lane >> 4) << 2;
        const int cl = lane & 15;
        float* base = red + wave * 1056;
#pragma unroll
        for (int j = 0; j < 4; ++j) {
            base[(rq + j) * 33 + cl]           = acc00[j];
            base[(rq + j) * 33 + 16 + cl]      = acc01[j];
            base[(16 + rq + j) * 33 + cl]      = acc10[j];
            base[(16 + rq + j) * 33 + 16 + cl] = acc11[j];
        }
    }
    __syncthreads();
#pragma unroll
    for (int k = 0; k < 4; ++k) {
        int el = tid + 256 * k;
        int row = el >> 5, col = el & 31;
        int o = row * 33 + col;
        float sv = red[o] + red[1056 + o] + red[2112 + o] + red[3168 + o];
        psum[(size_t)bid * (C * C) + el] = sv;
    }
    if (tid < C) {
        float s = red[4224 + tid] + red[4224 + C + tid] +
                  red[4224 + 2 * C + tid] + red[4224 + 3 * C + tid];
        prow[(size_t)bid * C + tid] = s;
    }
}

__global__ __launch_bounds__(256) void k2_ns(const float* __restrict__ psum,
                                             const float* __restrict__ prow,
                                             float* __restrict__ MT,
                                             float* __restrict__ vout) {
    __shared__ float S[C][C + 1];
    __shared__ float B[C][C + 1];
    __shared__ float T1[C][C + 1];
    __shared__ float T2[C][C + 1];
    __shared__ float mean[C];
    __shared__ float redw[4];
    __shared__ float normsh;
    const int g   = blockIdx.x;
    const int tid = threadIdx.x;
    const int e   = tid & 31;
    const int cbq = tid >> 5;
    float selt[4];
#pragma unroll
    for (int k = 0; k < 4; ++k) {
        int el = tid + 256 * k;
        float s = 0.f;
#pragma unroll
        for (int ch = 0; ch < NCH; ++ch)
            s += psum[((size_t)g * NCH + ch) * (C * C) + el];
        selt[k] = s;
    }
    if (tid < C) {
        float s = 0.f;
#pragma unroll
        for (int ch = 0; ch < NCH; ++ch)
            s += prow[((size_t)g * NCH + ch) * C + tid];
        mean[tid] = s / (float)D;
    }
    __syncthreads();
    float ss = 0.f;
#pragma unroll
    for (int k = 0; k < 4; ++k) {
        int el = tid + 256 * k;
        int c = el >> 5;
        float sv = selt[k] - (float)D * mean[c] * mean[e];
        if (c == e) sv += EPS;
        S[c][e] = sv;
        ss = fmaf(sv, sv, ss);
    }
#pragma unroll
    for (int off = 32; off >= 1; off >>= 1) ss += __shfl_xor(ss, off, 64);
    if ((tid & 63) == 0) redw[tid >> 6] = ss;
    __syncthreads();
    if (tid == 0) normsh = sqrtf(redw[0] + redw[1] + redw[2] + redw[3]);
    __syncthreads();
    const float inv_norm = 1.0f / normsh;
#pragma unroll
    for (int k = 0; k < 4; ++k) {
        int c = cbq + 8 * k;
        S[c][e] *= inv_norm;
        B[c][e] = (c == e) ? 1.f : 0.f;
    }
    __syncthreads();
    for (int it = 0; it < NS_ITERS; ++it) {
#pragma unroll
        for (int k = 0; k < 4; ++k) {
            int c = cbq + 8 * k;
            float s = 0.f;
            for (int kk = 0; kk < C; ++kk)
                s = fmaf(B[c][kk], B[kk][e], s);
            T1[c][e] = s;
        }
        __syncthreads();
#pragma unroll
        for (int k = 0; k < 4; ++k) {
            int c = cbq + 8 * k;
            float s = 0.f;
            for (int kk = 0; kk < C; ++kk)
                s = fmaf(T1[c][kk], B[kk][e], s);
            T2[c][e] = s;
        }
        __syncthreads();
        float pv[4];
#pragma unroll
        for (int k = 0; k < 4; ++k) {
            int c = cbq + 8 * k;
            float s = 0.f;
            for (int kk = 0; kk < C; ++kk)
                s = fmaf(T2[c][kk], S[kk][e], s);
            pv[k] = s;
        }
#pragma unroll
        for (int k = 0; k < 4; ++k) {
            int c = cbq + 8 * k;
            B[c][e] = 1.5f * B[c][e] - 0.5f * pv[k];
        }
        __syncthreads();
    }
    const float invs = 1.0f / sqrtf(normsh);
#pragma unroll
    for (int k = 0; k < 4; ++k) {
        int c = cbq + 8 * k;
        MT[(size_t)g * (C * C) + e * C + c] = B[c][e] * invs;
    }
    if (tid < C) {
        float s = 0.f;
        for (int ee = 0; ee < C; ++ee)
            s = fmaf(B[tid][ee] * invs, mean[ee], s);
        vout[(size_t)g * C + tid] = s;
    }
}

__global__ __launch_bounds__(256) void k3_apply(const float* __restrict__ W,
                                                const float* __restrict__ MT,
                                                const float* __restrict__ vv,
                                                float* __restrict__ out) {
    const int bpg = D / 1024;
    const int g   = blockIdx.x / bpg;
    const int cbk = blockIdx.x % bpg;
    const int d0  = cbk * 1024 + (int)threadIdx.x * 4;
    const float* Zg = W + (size_t)g * C * D + d0;
    const float* Mg = MT + (size_t)g * (C * C);
    float4 acc[C];
#pragma unroll
    for (int r = 0; r < C; ++r) acc[r] = make_float4(0.f, 0.f, 0.f, 0.f);
#pragma unroll 4
    for (int e = 0; e < C; ++e) {
        float4 z = *(const float4*)(Zg + (size_t)e * D);
#pragma unroll
        for (int r = 0; r < C; ++r) {
            float m = Mg[e * C + r];
            acc[r].x = fmaf(m, z.x, acc[r].x);
            acc[r].y = fmaf(m, z.y, acc[r].y);
            acc[r].z = fmaf(m, z.z, acc[r].z);
            acc[r].w = fmaf(m, z.w, acc[r].w);
        }
    }
    float* Og = out + (size_t)g * C * D + d0;
#pragma unroll
    for (int r = 0; r < C; ++r) {
        float vr = vv[g * C + r];
        float4 o = make_float4(acc[r].x - vr, acc[r].y - vr,
                               acc[r].z - vr, acc[r].w - vr);
        *(float4*)(Og + (size_t)r * D) = o;
    }
}

extern "C" void kernel_launch(void* const* d_in, const int* in_sizes, int n_in,
                              void* d_out, int out_size, void* d_ws, size_t ws_size,
                              hipStream_t stream) {
    const float* w = (const float*)d_in[0];
    float* out = (float*)d_out;

    const size_t fused_need = (size_t)(256 * 1024 + 256 * 32) * 2 * sizeof(float);
    bool done = false;
    if (ws_size >= fused_need) {
        float* psum = (float*)d_ws;                 // 256*1024
        float* prow = psum + 256 * 1024;            // 256*32
        float* mtb  = prow + 256 * 32;              // 256*1024
        float* vvb  = mtb + 256 * 1024;             // 256*32
        void* args[] = {(void*)&w, (void*)&psum, (void*)&prow,
                        (void*)&mtb, (void*)&vvb, (void*)&out};
        hipError_t err = hipLaunchCooperativeKernel((void*)fused_all, dim3(256),
                                                    dim3(512), args, 0, stream);
        done = (err == hipSuccess);
    }
    if (!done) {
        float* psum = (float*)d_ws;
        float* prow = psum + (size_t)(G * NCH) * (C * C);
        float* MT   = prow + (size_t)(G * NCH) * C;
        float* vv   = MT + (size_t)G * (C * C);
        k1_gram<<<dim3(NCH, G), 256, 0, stream>>>(w, psum, prow);
        k2_ns<<<G, 256, 0, stream>>>(psum, prow, MT, vv);
        k3_apply<<<G * (D / 1024), 256, 0, stream>>>(w, MT, vv, out);
    }
}